// Round 3
// baseline (501.408 us; speedup 1.0000x reference)
//
#include <hip/hip_runtime.h>

#define B_  8
#define S_  1024
#define D_  1024
#define H_  16
#define HD_ 64
#define M_  8192           // B*S
#define LOG2E 1.44269504088896f
#define QSCALE_ (0.125f * 1.44269504088896f)   // fold scale*log2e into Q
#define MSHIFT_ 20.0f      // static softmax shift (log2 domain)

typedef __attribute__((ext_vector_type(8))) short bf16x8;
typedef __attribute__((ext_vector_type(4))) float f32x4;

__device__ __forceinline__ unsigned short f2b(float x) {
  union { float f; unsigned u; } un; un.f = x;
  unsigned r = un.u + 0x7FFFu + ((un.u >> 16) & 1u);  // RNE
  return (unsigned short)(r >> 16);
}

// ---------------- kernel 0: hidden_states f32 -> bf16 ----------------
__global__ __launch_bounds__(256) void k_convert_x(const float* __restrict__ x,
                                                   unsigned short* __restrict__ o) {
  int i = (blockIdx.x * 256 + threadIdx.x) * 4;
  const int n = M_ * D_;
  const int stride = gridDim.x * 256 * 4;
  for (; i < n; i += stride) {
    const float4 v = *(const float4*)(x + i);
    ushort4 r;
    r.x = f2b(v.x); r.y = f2b(v.y); r.z = f2b(v.z); r.w = f2b(v.w);
    *(ushort4*)(o + i) = r;
  }
}

// ---------------- kernel 1: W (K x N) -> Wt bf16 (N x K), 3 matrices ----------------
__global__ __launch_bounds__(256) void k_transpose_w(const float* __restrict__ Wq,
    const float* __restrict__ Wk, const float* __restrict__ Wv,
    unsigned short* __restrict__ Wt) {
  __shared__ float t[64][65];
  const float* W = (blockIdx.z == 0) ? Wq : ((blockIdx.z == 1) ? Wk : Wv);
  unsigned short* dst = Wt + (size_t)blockIdx.z * (D_ * D_);
  const int k0 = blockIdx.x * 64, n0 = blockIdx.y * 64;
  const int tid = threadIdx.x;
#pragma unroll
  for (int i = 0; i < 16; ++i) {
    const int lin = i * 256 + tid;
    const int r = lin >> 6, c = lin & 63;
    t[r][c] = W[(size_t)(k0 + r) * D_ + n0 + c];
  }
  __syncthreads();
#pragma unroll
  for (int i = 0; i < 16; ++i) {
    const int lin = i * 256 + tid;
    const int r = lin >> 6, c = lin & 63;
    dst[(size_t)(n0 + r) * D_ + k0 + c] = f2b(t[c][r]);
  }
}

// ---------------- kernel 2: projection GEMM (m97 structure, 128x128x32) ----------------
template <int MODE>
__global__ __launch_bounds__(256) void k_proj(const unsigned short* __restrict__ X,
    const unsigned short* __restrict__ Wt,
    const float* __restrict__ bq, const float* __restrict__ bk, const float* __restrict__ bv,
    unsigned short* __restrict__ Qw, unsigned short* __restrict__ Kw,
    unsigned short* __restrict__ Vt) {
  __shared__ unsigned short xs[128 * 32];
  __shared__ unsigned short wsh[128 * 32];
  const int tid = threadIdx.x;
  const int lane = tid & 63, wv = tid >> 6;
  const int g = lane >> 4, li = lane & 15;
  const int m0 = blockIdx.x * 128;
  const int n0 = blockIdx.y * 128;
  const int wr = wv >> 1, wc = wv & 1;
  const int wtrow0 = (MODE == 0) ? n0 : (2048 + n0);

  f32x4 acc[4][4];
#pragma unroll
  for (int i = 0; i < 4; ++i)
#pragma unroll
    for (int j = 0; j < 4; ++j) acc[i][j] = (f32x4){0.f, 0.f, 0.f, 0.f};

  const int srow = wv * 32 + (lane >> 2);
  const int skel = (lane & 3) * 8;

  for (int k0 = 0; k0 < D_; k0 += 32) {
#pragma unroll
    for (int i = 0; i < 2; ++i) {
      const unsigned short* gx = X + (size_t)(m0 + srow + i * 16) * D_ + k0 + skel;
      const unsigned short* gw = Wt + (size_t)(wtrow0 + srow + i * 16) * D_ + k0 + skel;
      __builtin_amdgcn_global_load_lds(
          (const __attribute__((address_space(1))) void*)gx,
          (__attribute__((address_space(3))) void*)&xs[(wv * 32 + i * 16) * 32], 16, 0, 0);
      __builtin_amdgcn_global_load_lds(
          (const __attribute__((address_space(1))) void*)gw,
          (__attribute__((address_space(3))) void*)&wsh[(wv * 32 + i * 16) * 32], 16, 0, 0);
    }
    __syncthreads();
    bf16x8 af[4], bfr[4];
#pragma unroll
    for (int i = 0; i < 4; ++i) {
      const int ar = wr * 64 + i * 16 + li;
      const int br = wc * 64 + i * 16 + li;
      if (MODE == 0) {
        af[i]  = *(const bf16x8*)&xs[ar * 32 + g * 8];
        bfr[i] = *(const bf16x8*)&wsh[br * 32 + g * 8];
      } else {
        af[i]  = *(const bf16x8*)&wsh[ar * 32 + g * 8];
        bfr[i] = *(const bf16x8*)&xs[br * 32 + g * 8];
      }
    }
#pragma unroll
    for (int i = 0; i < 4; ++i)
#pragma unroll
      for (int j = 0; j < 4; ++j)
        acc[i][j] = __builtin_amdgcn_mfma_f32_16x16x32_bf16(af[i], bfr[j], acc[i][j], 0, 0, 0);
    __syncthreads();
  }

  if (MODE == 0) {
#pragma unroll
    for (int j = 0; j < 4; ++j) {
      const int n = n0 + wc * 64 + j * 16 + li;
      const float bias = (n < D_) ? bq[n] : bk[n - D_];
#pragma unroll
      for (int i = 0; i < 4; ++i) {
#pragma unroll
        for (int r = 0; r < 4; ++r) {
          const int m = m0 + wr * 64 + i * 16 + g * 4 + r;
          const float v = acc[i][j][r] + bias;
          const int bb = m >> 10, ss = m & 1023;
          if (n < D_) {
            Qw[((size_t)(bb * H_ + (n >> 6)) * S_ + ss) * HD_ + (n & 63)] = f2b(v * QSCALE_);
          } else {
            const int nk = n - D_;
            Kw[((size_t)(bb * H_ + (nk >> 6)) * S_ + ss) * HD_ + (nk & 63)] = f2b(v);
          }
        }
      }
    }
  } else {
#pragma unroll
    for (int i = 0; i < 4; ++i) {
#pragma unroll
      for (int r = 0; r < 4; ++r) {
        const int nv = n0 + wr * 64 + i * 16 + g * 4 + r;
        const float bias = bv[nv];
#pragma unroll
        for (int j = 0; j < 4; ++j) {
          const int m = m0 + wc * 64 + j * 16 + li;
          const int bb = m >> 10, ss = m & 1023;
          const float v = acc[i][j][r] + bias;
          Vt[((size_t)(bb * H_ + (nv >> 6)) * HD_ + (nv & 63)) * S_ + ss] = f2b(v);
        }
      }
    }
  }
}

// ---------------- kernel 3: flash attention, swapped-QK, static-shift softmax ----------------
// Swapped MFMA: sa = mfma(K, Q) -> D[k][q]: q = lane&15, k = 4*(lane>>4)+reg.
// prev/mask load as float4 directly in this layout; prev 2-deep, mask 1-deep, K 1-deep prefetch.
__global__ __launch_bounds__(256, 4) void k_attn(const unsigned short* __restrict__ Qw,
    const unsigned short* __restrict__ Kw, const unsigned short* __restrict__ Vt,
    const float* __restrict__ prev, const float* __restrict__ mask,
    float* __restrict__ out) {
  __shared__ unsigned short p_lds[4][16][72];   // P bounce (q-row major), 144B rows
  const int tid = threadIdx.x;
  const int lane = tid & 63, wv = tid >> 6;
  const int g = lane >> 4, li = lane & 15;

  const int phys = blockIdx.x + 16 * blockIdx.y;  // 0..2047
  const int xcd = phys & 7, idx = phys >> 3;
  const int bh = xcd + 8 * (idx & 15);            // same-bh blocks share an XCD
  const int qt = idx >> 4;
  const int b = bh >> 4, h = bh & 15;
  const int q0 = qt * 64 + wv * 16;

  // Q fragment (B-operand now; same per-lane layout: row=li, k=g*8+e)
  bf16x8 qf[2];
  {
    const unsigned short* qp = Qw + ((size_t)bh * S_ + q0 + li) * HD_ + g * 8;
    qf[0] = *(const bf16x8*)qp;
    qf[1] = *(const bf16x8*)(qp + 32);
  }

  float lrun = 0.f;
  f32x4 ctx[4];
#pragma unroll
  for (int d = 0; d < 4; ++d) ctx[d] = (f32x4){0.f, 0.f, 0.f, 0.f};

  // per-lane row pointers: this lane consumes prev/mask row (q0+li), cols g*4 + cb*16
  const float* pb = prev + (size_t)bh * S_ * S_ + (size_t)(q0 + li) * S_ + g * 4;
  const float* mb = mask + (size_t)b * S_ * S_ + (size_t)(q0 + li) * S_ + g * 4;
  const unsigned short* kbase = Kw + (size_t)bh * S_ * HD_;
  const unsigned short* vbase = Vt + (size_t)bh * HD_ * S_;

  // ---- prologue: K tile 0; prev tiles 0,1; mask tile 0 ----
  bf16x8 kf[4][2];
#pragma unroll
  for (int cb = 0; cb < 4; ++cb) {
    const unsigned short* kp = kbase + (size_t)(cb * 16 + li) * HD_ + g * 8;
    kf[cb][0] = *(const bf16x8*)kp;
    kf[cb][1] = *(const bf16x8*)(kp + 32);
  }
  f32x4 pA[4], pB[4], mA[4];
#pragma unroll
  for (int cb = 0; cb < 4; ++cb) pA[cb] = __builtin_nontemporal_load((const f32x4*)(pb + cb * 16));
#pragma unroll
  for (int cb = 0; cb < 4; ++cb) pB[cb] = __builtin_nontemporal_load((const f32x4*)(pb + 64 + cb * 16));
#pragma unroll
  for (int cb = 0; cb < 4; ++cb) mA[cb] = *(const f32x4*)(mb + cb * 16);

#define ATTN_ITER(T, PC)                                                         \
  {                                                                              \
    const int s0 = (T) * 64;                                                     \
    const int sN = ((T) < 15 ? (T) + 1 : 15) * 64;                               \
    const int sP = ((T) < 14 ? (T) + 2 : 15) * 64;                               \
    /* V first half (d=0,1) issued early */                                      \
    bf16x8 vf[4][2];                                                             \
    _Pragma("unroll")                                                            \
    for (int d = 0; d < 2; ++d) {                                                \
      const unsigned short* vp = vbase + (size_t)(d * 16 + li) * S_ + s0 + g * 8;\
      vf[d][0] = *(const bf16x8*)vp;                                             \
      vf[d][1] = *(const bf16x8*)(vp + 32);                                      \
    }                                                                            \
    /* QK swapped: D[k][q] */                                                    \
    f32x4 sa[4];                                                                 \
    _Pragma("unroll")                                                            \
    for (int cb = 0; cb < 4; ++cb) {                                             \
      f32x4 z = (f32x4){0.f, 0.f, 0.f, 0.f};                                     \
      z      = __builtin_amdgcn_mfma_f32_16x16x32_bf16(kf[cb][0], qf[0], z, 0, 0, 0); \
      sa[cb] = __builtin_amdgcn_mfma_f32_16x16x32_bf16(kf[cb][1], qf[1], z, 0, 0, 0); \
    }                                                                            \
    /* K prefetch tile T+1 (reuses kf regs, dead after QK) */                    \
    _Pragma("unroll")                                                            \
    for (int cb = 0; cb < 4; ++cb) {                                             \
      const unsigned short* kp = kbase + (size_t)(sN + cb * 16 + li) * HD_ + g * 8; \
      kf[cb][0] = *(const bf16x8*)kp;                                            \
      kf[cb][1] = *(const bf16x8*)(kp + 32);                                     \
    }                                                                            \
    /* p = exp2(sa + (prev+mask)*log2e - 20); per-lane row-sum */                \
    _Pragma("unroll")                                                            \
    for (int cb = 0; cb < 4; ++cb) {                                             \
      f32x4 pmc;                                                                 \
      pmc.x = fmaf(PC[cb].x + mA[cb].x, LOG2E, -MSHIFT_);                        \
      pmc.y = fmaf(PC[cb].y + mA[cb].y, LOG2E, -MSHIFT_);                        \
      pmc.z = fmaf(PC[cb].z + mA[cb].z, LOG2E, -MSHIFT_);                        \
      pmc.w = fmaf(PC[cb].w + mA[cb].w, LOG2E, -MSHIFT_);                        \
      const float e0 = exp2f(sa[cb][0] + pmc.x);                                 \
      const float e1 = exp2f(sa[cb][1] + pmc.y);                                 \
      const float e2 = exp2f(sa[cb][2] + pmc.z);                                 \
      const float e3 = exp2f(sa[cb][3] + pmc.w);                                 \
      lrun += (e0 + e1) + (e2 + e3);                                             \
      ushort4 pw;                                                                \
      pw.x = f2b(e0); pw.y = f2b(e1); pw.z = f2b(e2); pw.w = f2b(e3);            \
      *(ushort4*)&p_lds[wv][li][cb * 16 + g * 4] = pw;                           \
    }                                                                            \
    /* mask prefetch T+1; prev prefetch T+2 (into consumed regs) */              \
    _Pragma("unroll")                                                            \
    for (int cb = 0; cb < 4; ++cb) mA[cb] = *(const f32x4*)(mb + sN + cb * 16);  \
    _Pragma("unroll")                                                            \
    for (int cb = 0; cb < 4; ++cb)                                               \
      PC[cb] = __builtin_nontemporal_load((const f32x4*)(pb + sP + cb * 16));    \
    /* V second half */                                                          \
    _Pragma("unroll")                                                            \
    for (int d = 2; d < 4; ++d) {                                                \
      const unsigned short* vp = vbase + (size_t)(d * 16 + li) * S_ + s0 + g * 8;\
      vf[d][0] = *(const bf16x8*)vp;                                             \
      vf[d][1] = *(const bf16x8*)(vp + 32);                                      \
    }                                                                            \
    /* P (A-layout) from per-wave bounce */                                      \
    bf16x8 pf0 = *(const bf16x8*)&p_lds[wv][li][g * 8];                          \
    bf16x8 pf1 = *(const bf16x8*)&p_lds[wv][li][32 + g * 8];                     \
    _Pragma("unroll")                                                            \
    for (int d = 0; d < 4; ++d) {                                                \
      ctx[d] = __builtin_amdgcn_mfma_f32_16x16x32_bf16(pf0, vf[d][0], ctx[d], 0, 0, 0); \
      ctx[d] = __builtin_amdgcn_mfma_f32_16x16x32_bf16(pf1, vf[d][1], ctx[d], 0, 0, 0); \
    }                                                                            \
  }

  for (int t = 0; t < 16; t += 2) {
    ATTN_ITER(t, pA);
    ATTN_ITER(t + 1, pB);
  }
#undef ATTN_ITER

  // row sums: combine the 4 g-groups (lanes li, li+16, li+32, li+48)
  lrun += __shfl_xor(lrun, 16);
  lrun += __shfl_xor(lrun, 32);
  // lane (g,li) holds ctx rows g*4+j; rowsum(r) lives at lanes with li==r
#pragma unroll
  for (int j = 0; j < 4; ++j) {
    const float rs = __shfl(lrun, g * 4 + j);
    const float inv = 1.0f / rs;
    const int q = q0 + g * 4 + j;
    float* op = out + ((size_t)b * S_ + q) * D_ + h * HD_ + li;
#pragma unroll
    for (int d = 0; d < 4; ++d)
      __builtin_nontemporal_store(ctx[d][j] * inv, op + d * 16);
  }
}

extern "C" void kernel_launch(void* const* d_in, const int* in_sizes, int n_in,
                              void* d_out, int out_size, void* d_ws, size_t ws_size,
                              hipStream_t stream) {
  const float* hs   = (const float*)d_in[0];
  const float* mask = (const float*)d_in[1];
  const float* prev = (const float*)d_in[2];
  const float* Wq   = (const float*)d_in[3];
  const float* bq   = (const float*)d_in[4];
  const float* Wk   = (const float*)d_in[5];
  const float* bk   = (const float*)d_in[6];
  const float* Wv   = (const float*)d_in[7];
  const float* bv   = (const float*)d_in[8];
  float* out = (float*)d_out;

  char* ws = (char*)d_ws;
  unsigned short* Xbf = (unsigned short*)ws;                    // 16 MB
  unsigned short* Wt  = (unsigned short*)(ws + (16ull << 20));  //  6 MB
  unsigned short* Qw  = (unsigned short*)(ws + (22ull << 20));  // 16 MB
  unsigned short* Kw  = (unsigned short*)(ws + (38ull << 20));  // 16 MB
  unsigned short* Vt  = (unsigned short*)(ws + (54ull << 20));  // 16 MB  (total 70 MB)

  k_convert_x<<<2048, 256, 0, stream>>>(hs, Xbf);
  k_transpose_w<<<dim3(16, 16, 3), 256, 0, stream>>>(Wq, Wk, Wv, Wt);
  k_proj<0><<<dim3(64, 16), 256, 0, stream>>>(Xbf, Wt, bq, bk, bv, Qw, Kw, Vt);
  k_proj<1><<<dim3(64, 8),  256, 0, stream>>>(Xbf, Wt, bq, bk, bv, Qw, Kw, Vt);
  k_attn<<<dim3(16, 128), 256, 0, stream>>>(Qw, Kw, Vt, prev, mask, out);
}

// Round 4
// 457.481 us; speedup vs baseline: 1.0960x; 1.0960x over previous
//
#include <hip/hip_runtime.h>

#define B_  8
#define S_  1024
#define D_  1024
#define H_  16
#define HD_ 64
#define M_  8192           // B*S
#define LOG2E 1.44269504088896f
#define QSCALE_ (0.125f * 1.44269504088896f)   // fold scale*log2e into Q
#define MSHIFT_ 20.0f      // static softmax shift (log2 domain)

typedef __attribute__((ext_vector_type(8))) short bf16x8;
typedef __attribute__((ext_vector_type(4))) float f32x4;

__device__ __forceinline__ unsigned short f2b(float x) {
  union { float f; unsigned u; } un; un.f = x;
  unsigned r = un.u + 0x7FFFu + ((un.u >> 16) & 1u);  // RNE
  return (unsigned short)(r >> 16);
}

// ---------------- kernel 0: hidden_states f32 -> bf16 ----------------
__global__ __launch_bounds__(256) void k_convert_x(const float* __restrict__ x,
                                                   unsigned short* __restrict__ o) {
  int i = (blockIdx.x * 256 + threadIdx.x) * 4;
  const int n = M_ * D_;
  const int stride = gridDim.x * 256 * 4;
  for (; i < n; i += stride) {
    const float4 v = *(const float4*)(x + i);
    ushort4 r;
    r.x = f2b(v.x); r.y = f2b(v.y); r.z = f2b(v.z); r.w = f2b(v.w);
    *(ushort4*)(o + i) = r;
  }
}

// ---------------- kernel 1: W (K x N) -> Wt bf16 (N x K), 3 matrices ----------------
__global__ __launch_bounds__(256) void k_transpose_w(const float* __restrict__ Wq,
    const float* __restrict__ Wk, const float* __restrict__ Wv,
    unsigned short* __restrict__ Wt) {
  __shared__ float t[64][65];
  const float* W = (blockIdx.z == 0) ? Wq : ((blockIdx.z == 1) ? Wk : Wv);
  unsigned short* dst = Wt + (size_t)blockIdx.z * (D_ * D_);
  const int k0 = blockIdx.x * 64, n0 = blockIdx.y * 64;
  const int tid = threadIdx.x;
#pragma unroll
  for (int i = 0; i < 16; ++i) {
    const int lin = i * 256 + tid;
    const int r = lin >> 6, c = lin & 63;
    t[r][c] = W[(size_t)(k0 + r) * D_ + n0 + c];
  }
  __syncthreads();
#pragma unroll
  for (int i = 0; i < 16; ++i) {
    const int lin = i * 256 + tid;
    const int r = lin >> 6, c = lin & 63;
    dst[(size_t)(n0 + r) * D_ + k0 + c] = f2b(t[c][r]);
  }
}

// ---------------- kernel 2: projection GEMM (m97 structure, 128x128x32) ----------------
template <int MODE>
__global__ __launch_bounds__(256) void k_proj(const unsigned short* __restrict__ X,
    const unsigned short* __restrict__ Wt,
    const float* __restrict__ bq, const float* __restrict__ bk, const float* __restrict__ bv,
    unsigned short* __restrict__ Qw, unsigned short* __restrict__ Kw,
    unsigned short* __restrict__ Vt) {
  __shared__ unsigned short xs[128 * 32];
  __shared__ unsigned short wsh[128 * 32];
  const int tid = threadIdx.x;
  const int lane = tid & 63, wv = tid >> 6;
  const int g = lane >> 4, li = lane & 15;
  const int m0 = blockIdx.x * 128;
  const int n0 = blockIdx.y * 128;
  const int wr = wv >> 1, wc = wv & 1;
  const int wtrow0 = (MODE == 0) ? n0 : (2048 + n0);

  f32x4 acc[4][4];
#pragma unroll
  for (int i = 0; i < 4; ++i)
#pragma unroll
    for (int j = 0; j < 4; ++j) acc[i][j] = (f32x4){0.f, 0.f, 0.f, 0.f};

  const int srow = wv * 32 + (lane >> 2);
  const int skel = (lane & 3) * 8;

  for (int k0 = 0; k0 < D_; k0 += 32) {
#pragma unroll
    for (int i = 0; i < 2; ++i) {
      const unsigned short* gx = X + (size_t)(m0 + srow + i * 16) * D_ + k0 + skel;
      const unsigned short* gw = Wt + (size_t)(wtrow0 + srow + i * 16) * D_ + k0 + skel;
      __builtin_amdgcn_global_load_lds(
          (const __attribute__((address_space(1))) void*)gx,
          (__attribute__((address_space(3))) void*)&xs[(wv * 32 + i * 16) * 32], 16, 0, 0);
      __builtin_amdgcn_global_load_lds(
          (const __attribute__((address_space(1))) void*)gw,
          (__attribute__((address_space(3))) void*)&wsh[(wv * 32 + i * 16) * 32], 16, 0, 0);
    }
    __syncthreads();
    bf16x8 af[4], bfr[4];
#pragma unroll
    for (int i = 0; i < 4; ++i) {
      const int ar = wr * 64 + i * 16 + li;
      const int br = wc * 64 + i * 16 + li;
      if (MODE == 0) {
        af[i]  = *(const bf16x8*)&xs[ar * 32 + g * 8];
        bfr[i] = *(const bf16x8*)&wsh[br * 32 + g * 8];
      } else {
        af[i]  = *(const bf16x8*)&wsh[ar * 32 + g * 8];
        bfr[i] = *(const bf16x8*)&xs[br * 32 + g * 8];
      }
    }
#pragma unroll
    for (int i = 0; i < 4; ++i)
#pragma unroll
      for (int j = 0; j < 4; ++j)
        acc[i][j] = __builtin_amdgcn_mfma_f32_16x16x32_bf16(af[i], bfr[j], acc[i][j], 0, 0, 0);
    __syncthreads();
  }

  if (MODE == 0) {
#pragma unroll
    for (int j = 0; j < 4; ++j) {
      const int n = n0 + wc * 64 + j * 16 + li;
      const float bias = (n < D_) ? bq[n] : bk[n - D_];
#pragma unroll
      for (int i = 0; i < 4; ++i) {
#pragma unroll
        for (int r = 0; r < 4; ++r) {
          const int m = m0 + wr * 64 + i * 16 + g * 4 + r;
          const float v = acc[i][j][r] + bias;
          const int bb = m >> 10, ss = m & 1023;
          if (n < D_) {
            Qw[((size_t)(bb * H_ + (n >> 6)) * S_ + ss) * HD_ + (n & 63)] = f2b(v * QSCALE_);
          } else {
            const int nk = n - D_;
            Kw[((size_t)(bb * H_ + (nk >> 6)) * S_ + ss) * HD_ + (nk & 63)] = f2b(v);
          }
        }
      }
    }
  } else {
#pragma unroll
    for (int i = 0; i < 4; ++i) {
#pragma unroll
      for (int r = 0; r < 4; ++r) {
        const int nv = n0 + wr * 64 + i * 16 + g * 4 + r;
        const float bias = bv[nv];
#pragma unroll
        for (int j = 0; j < 4; ++j) {
          const int m = m0 + wc * 64 + j * 16 + li;
          const int bb = m >> 10, ss = m & 1023;
          const float v = acc[i][j][r] + bias;
          Vt[((size_t)(bb * H_ + (nv >> 6)) * HD_ + (nv & 63)) * S_ + ss] = f2b(v);
        }
      }
    }
  }
}

// ---------------- kernel 3: flash attention, swapped-QK, static-shift softmax ----------------
// sa = mfma(K, Q) -> D[k][q]: q = lane&15, k = 4*(lane>>4)+reg (prev/mask in native layout).
// Issue order per iter: K(t), V(t), mask(t) first; prev(t+2) AFTER the QK MFMAs so no
// consumer wait drains the prev prefetch (FIFO vmcnt). No nontemporal anywhere.
__global__ __launch_bounds__(256, 3) void k_attn(const unsigned short* __restrict__ Qw,
    const unsigned short* __restrict__ Kw, const unsigned short* __restrict__ Vt,
    const float* __restrict__ prev, const float* __restrict__ mask,
    float* __restrict__ out) {
  __shared__ unsigned short p_lds[4][16][72];   // P bounce (q-row major), 144B rows
  const int tid = threadIdx.x;
  const int lane = tid & 63, wv = tid >> 6;
  const int g = lane >> 4, li = lane & 15;

  const int phys = blockIdx.x + 16 * blockIdx.y;  // 0..2047
  const int xcd = phys & 7, idx = phys >> 3;
  const int qt = idx & 15;                        // consecutive same-XCD blocks: same bh
  const int bh = xcd + 8 * (idx >> 4);
  const int b = bh >> 4, h = bh & 15;
  const int q0 = qt * 64 + wv * 16;

  // Q fragment (B-operand; row=li, k=g*8+e), pre-scaled by SCALE*LOG2E
  bf16x8 qf[2];
  {
    const unsigned short* qp = Qw + ((size_t)bh * S_ + q0 + li) * HD_ + g * 8;
    qf[0] = *(const bf16x8*)qp;
    qf[1] = *(const bf16x8*)(qp + 32);
  }

  float lrun = 0.f;
  f32x4 ctx[4];
#pragma unroll
  for (int d = 0; d < 4; ++d) ctx[d] = (f32x4){0.f, 0.f, 0.f, 0.f};

  // per-lane: this lane consumes prev/mask row (q0+li), cols cb*16 + g*4
  const float* pb = prev + (size_t)bh * S_ * S_ + (size_t)(q0 + li) * S_ + g * 4;
  const float* mb = mask + (size_t)b * S_ * S_ + (size_t)(q0 + li) * S_ + g * 4;
  const unsigned short* kbase = Kw + (size_t)bh * S_ * HD_;
  const unsigned short* vbase = Vt + (size_t)bh * HD_ * S_;

  // ---- prologue: prev tiles 0,1 (2-deep) ----
  f32x4 pA[4], pB[4];
#pragma unroll
  for (int cb = 0; cb < 4; ++cb) pA[cb] = *(const f32x4*)(pb + cb * 16);
#pragma unroll
  for (int cb = 0; cb < 4; ++cb) pB[cb] = *(const f32x4*)(pb + 64 + cb * 16);

#define ATTN_ITER(T, PC)                                                         \
  {                                                                              \
    const int s0 = (T) * 64;                                                     \
    const int sP = ((T) + 2 < 16 ? (T) + 2 : (T)) * 64;                          \
    /* K(t) — L2-resident */                                                     \
    bf16x8 kf[4][2];                                                             \
    _Pragma("unroll")                                                            \
    for (int cb = 0; cb < 4; ++cb) {                                             \
      const unsigned short* kp = kbase + (size_t)(s0 + cb * 16 + li) * HD_ + g * 8; \
      kf[cb][0] = *(const bf16x8*)kp;                                            \
      kf[cb][1] = *(const bf16x8*)(kp + 32);                                     \
    }                                                                            \
    /* V(t) — L2-resident */                                                     \
    bf16x8 vf[4][2];                                                             \
    _Pragma("unroll")                                                            \
    for (int d = 0; d < 4; ++d) {                                                \
      const unsigned short* vp = vbase + (size_t)(d * 16 + li) * S_ + s0 + g * 8;\
      vf[d][0] = *(const bf16x8*)vp;                                             \
      vf[d][1] = *(const bf16x8*)(vp + 32);                                      \
    }                                                                            \
    /* mask(t) — L3-resident */                                                  \
    f32x4 mA[4];                                                                 \
    _Pragma("unroll")                                                            \
    for (int cb = 0; cb < 4; ++cb) mA[cb] = *(const f32x4*)(mb + s0 + cb * 16);  \
    /* QK swapped: D[k][q] */                                                    \
    f32x4 sa[4];                                                                 \
    _Pragma("unroll")                                                            \
    for (int cb = 0; cb < 4; ++cb) {                                             \
      f32x4 z = (f32x4){0.f, 0.f, 0.f, 0.f};                                     \
      z      = __builtin_amdgcn_mfma_f32_16x16x32_bf16(kf[cb][0], qf[0], z, 0, 0, 0); \
      sa[cb] = __builtin_amdgcn_mfma_f32_16x16x32_bf16(kf[cb][1], qf[1], z, 0, 0, 0); \
    }                                                                            \
    /* prev(t+2) issued AFTER QK: consumer waits never drain it */               \
    f32x4 pN[4];                                                                 \
    _Pragma("unroll")                                                            \
    for (int cb = 0; cb < 4; ++cb) pN[cb] = *(const f32x4*)(pb + sP + cb * 16);  \
    /* p = exp2(sa + (prev+mask)*log2e - 20); per-lane row-sum */                \
    _Pragma("unroll")                                                            \
    for (int cb = 0; cb < 4; ++cb) {                                             \
      f32x4 pmc;                                                                 \
      pmc.x = fmaf(PC[cb].x + mA[cb].x, LOG2E, -MSHIFT_);                        \
      pmc.y = fmaf(PC[cb].y + mA[cb].y, LOG2E, -MSHIFT_);                        \
      pmc.z = fmaf(PC[cb].z + mA[cb].z, LOG2E, -MSHIFT_);                        \
      pmc.w = fmaf(PC[cb].w + mA[cb].w, LOG2E, -MSHIFT_);                        \
      const float e0 = exp2f(sa[cb][0] + pmc.x);                                 \
      const float e1 = exp2f(sa[cb][1] + pmc.y);                                 \
      const float e2 = exp2f(sa[cb][2] + pmc.z);                                 \
      const float e3 = exp2f(sa[cb][3] + pmc.w);                                 \
      lrun += (e0 + e1) + (e2 + e3);                                             \
      ushort4 pw;                                                                \
      pw.x = f2b(e0); pw.y = f2b(e1); pw.z = f2b(e2); pw.w = f2b(e3);            \
      *(ushort4*)&p_lds[wv][li][cb * 16 + g * 4] = pw;                           \
    }                                                                            \
    _Pragma("unroll")                                                            \
    for (int cb = 0; cb < 4; ++cb) PC[cb] = pN[cb];                              \
    /* P (A-layout) from per-wave bounce */                                      \
    bf16x8 pf0 = *(const bf16x8*)&p_lds[wv][li][g * 8];                          \
    bf16x8 pf1 = *(const bf16x8*)&p_lds[wv][li][32 + g * 8];                     \
    _Pragma("unroll")                                                            \
    for (int d = 0; d < 4; ++d) {                                                \
      ctx[d] = __builtin_amdgcn_mfma_f32_16x16x32_bf16(pf0, vf[d][0], ctx[d], 0, 0, 0); \
      ctx[d] = __builtin_amdgcn_mfma_f32_16x16x32_bf16(pf1, vf[d][1], ctx[d], 0, 0, 0); \
    }                                                                            \
  }

  for (int t = 0; t < 16; t += 2) {
    ATTN_ITER(t, pA);
    ATTN_ITER(t + 1, pB);
  }
#undef ATTN_ITER

  // row sums: combine the 4 g-groups (lane li holds partial for q-row li)
  lrun += __shfl_xor(lrun, 16);
  lrun += __shfl_xor(lrun, 32);
#pragma unroll
  for (int j = 0; j < 4; ++j) {
    const float rs = __shfl(lrun, g * 4 + j);
    const float inv = 1.0f / rs;
    const int q = q0 + g * 4 + j;
    float* op = out + ((size_t)b * S_ + q) * D_ + h * HD_ + li;
#pragma unroll
    for (int d = 0; d < 4; ++d)
      op[d * 16] = ctx[d][j] * inv;
  }
}

extern "C" void kernel_launch(void* const* d_in, const int* in_sizes, int n_in,
                              void* d_out, int out_size, void* d_ws, size_t ws_size,
                              hipStream_t stream) {
  const float* hs   = (const float*)d_in[0];
  const float* mask = (const float*)d_in[1];
  const float* prev = (const float*)d_in[2];
  const float* Wq   = (const float*)d_in[3];
  const float* bq   = (const float*)d_in[4];
  const float* Wk   = (const float*)d_in[5];
  const float* bk   = (const float*)d_in[6];
  const float* Wv   = (const float*)d_in[7];
  const float* bv   = (const float*)d_in[8];
  float* out = (float*)d_out;

  char* ws = (char*)d_ws;
  unsigned short* Xbf = (unsigned short*)ws;                    // 16 MB
  unsigned short* Wt  = (unsigned short*)(ws + (16ull << 20));  //  6 MB
  unsigned short* Qw  = (unsigned short*)(ws + (22ull << 20));  // 16 MB
  unsigned short* Kw  = (unsigned short*)(ws + (38ull << 20));  // 16 MB
  unsigned short* Vt  = (unsigned short*)(ws + (54ull << 20));  // 16 MB  (total 70 MB)

  k_convert_x<<<2048, 256, 0, stream>>>(hs, Xbf);
  k_transpose_w<<<dim3(16, 16, 3), 256, 0, stream>>>(Wq, Wk, Wv, Wt);
  k_proj<0><<<dim3(64, 16), 256, 0, stream>>>(Xbf, Wt, bq, bk, bv, Qw, Kw, Vt);
  k_proj<1><<<dim3(64, 8),  256, 0, stream>>>(Xbf, Wt, bq, bk, bv, Qw, Kw, Vt);
  k_attn<<<dim3(16, 128), 256, 0, stream>>>(Qw, Kw, Vt, prev, mask, out);
}

// Round 5
// 438.610 us; speedup vs baseline: 1.1432x; 1.0430x over previous
//
#include <hip/hip_runtime.h>

#define B_  8
#define S_  1024
#define D_  1024
#define H_  16
#define HD_ 64
#define M_  8192           // B*S
#define LOG2E 1.44269504088896f
#define QSCALE_ (0.125f * 1.44269504088896f)   // fold scale*log2e into Q
#define MSHIFT_ 20.0f      // static softmax shift (log2 domain)

typedef __attribute__((ext_vector_type(8))) short bf16x8;
typedef __attribute__((ext_vector_type(4))) float f32x4;

__device__ __forceinline__ unsigned short f2b(float x) {
  union { float f; unsigned u; } un; un.f = x;
  unsigned r = un.u + 0x7FFFu + ((un.u >> 16) & 1u);  // RNE
  return (unsigned short)(r >> 16);
}

// ---------------- kernel 0: hidden_states f32 -> bf16 ----------------
__global__ __launch_bounds__(256) void k_convert_x(const float* __restrict__ x,
                                                   unsigned short* __restrict__ o) {
  int i = (blockIdx.x * 256 + threadIdx.x) * 4;
  const int n = M_ * D_;
  const int stride = gridDim.x * 256 * 4;
  for (; i < n; i += stride) {
    const float4 v = *(const float4*)(x + i);
    ushort4 r;
    r.x = f2b(v.x); r.y = f2b(v.y); r.z = f2b(v.z); r.w = f2b(v.w);
    *(ushort4*)(o + i) = r;
  }
}

// ---------------- kernel 1: W (K x N) -> Wt bf16 (N x K), 3 matrices ----------------
__global__ __launch_bounds__(256) void k_transpose_w(const float* __restrict__ Wq,
    const float* __restrict__ Wk, const float* __restrict__ Wv,
    unsigned short* __restrict__ Wt) {
  __shared__ float t[64][65];
  const float* W = (blockIdx.z == 0) ? Wq : ((blockIdx.z == 1) ? Wk : Wv);
  unsigned short* dst = Wt + (size_t)blockIdx.z * (D_ * D_);
  const int k0 = blockIdx.x * 64, n0 = blockIdx.y * 64;
  const int tid = threadIdx.x;
#pragma unroll
  for (int i = 0; i < 16; ++i) {
    const int lin = i * 256 + tid;
    const int r = lin >> 6, c = lin & 63;
    t[r][c] = W[(size_t)(k0 + r) * D_ + n0 + c];
  }
  __syncthreads();
#pragma unroll
  for (int i = 0; i < 16; ++i) {
    const int lin = i * 256 + tid;
    const int r = lin >> 6, c = lin & 63;
    dst[(size_t)(n0 + r) * D_ + k0 + c] = f2b(t[c][r]);
  }
}

// ---------------- kernel 2: projection GEMM (m97 structure, 128x128x32) ----------------
template <int MODE>
__global__ __launch_bounds__(256) void k_proj(const unsigned short* __restrict__ X,
    const unsigned short* __restrict__ Wt,
    const float* __restrict__ bq, const float* __restrict__ bk, const float* __restrict__ bv,
    unsigned short* __restrict__ Qw, unsigned short* __restrict__ Kw,
    unsigned short* __restrict__ Vt) {
  __shared__ unsigned short xs[128 * 32];
  __shared__ unsigned short wsh[128 * 32];
  const int tid = threadIdx.x;
  const int lane = tid & 63, wv = tid >> 6;
  const int g = lane >> 4, li = lane & 15;
  const int m0 = blockIdx.x * 128;
  const int n0 = blockIdx.y * 128;
  const int wr = wv >> 1, wc = wv & 1;
  const int wtrow0 = (MODE == 0) ? n0 : (2048 + n0);

  f32x4 acc[4][4];
#pragma unroll
  for (int i = 0; i < 4; ++i)
#pragma unroll
    for (int j = 0; j < 4; ++j) acc[i][j] = (f32x4){0.f, 0.f, 0.f, 0.f};

  const int srow = wv * 32 + (lane >> 2);
  const int skel = (lane & 3) * 8;

  for (int k0 = 0; k0 < D_; k0 += 32) {
#pragma unroll
    for (int i = 0; i < 2; ++i) {
      const unsigned short* gx = X + (size_t)(m0 + srow + i * 16) * D_ + k0 + skel;
      const unsigned short* gw = Wt + (size_t)(wtrow0 + srow + i * 16) * D_ + k0 + skel;
      __builtin_amdgcn_global_load_lds(
          (const __attribute__((address_space(1))) void*)gx,
          (__attribute__((address_space(3))) void*)&xs[(wv * 32 + i * 16) * 32], 16, 0, 0);
      __builtin_amdgcn_global_load_lds(
          (const __attribute__((address_space(1))) void*)gw,
          (__attribute__((address_space(3))) void*)&wsh[(wv * 32 + i * 16) * 32], 16, 0, 0);
    }
    __syncthreads();
    bf16x8 af[4], bfr[4];
#pragma unroll
    for (int i = 0; i < 4; ++i) {
      const int ar = wr * 64 + i * 16 + li;
      const int br = wc * 64 + i * 16 + li;
      if (MODE == 0) {
        af[i]  = *(const bf16x8*)&xs[ar * 32 + g * 8];
        bfr[i] = *(const bf16x8*)&wsh[br * 32 + g * 8];
      } else {
        af[i]  = *(const bf16x8*)&wsh[ar * 32 + g * 8];
        bfr[i] = *(const bf16x8*)&xs[br * 32 + g * 8];
      }
    }
#pragma unroll
    for (int i = 0; i < 4; ++i)
#pragma unroll
      for (int j = 0; j < 4; ++j)
        acc[i][j] = __builtin_amdgcn_mfma_f32_16x16x32_bf16(af[i], bfr[j], acc[i][j], 0, 0, 0);
    __syncthreads();
  }

  if (MODE == 0) {
#pragma unroll
    for (int j = 0; j < 4; ++j) {
      const int n = n0 + wc * 64 + j * 16 + li;
      const float bias = (n < D_) ? bq[n] : bk[n - D_];
#pragma unroll
      for (int i = 0; i < 4; ++i) {
#pragma unroll
        for (int r = 0; r < 4; ++r) {
          const int m = m0 + wr * 64 + i * 16 + g * 4 + r;
          const float v = acc[i][j][r] + bias;
          const int bb = m >> 10, ss = m & 1023;
          if (n < D_) {
            Qw[((size_t)(bb * H_ + (n >> 6)) * S_ + ss) * HD_ + (n & 63)] = f2b(v * QSCALE_);
          } else {
            const int nk = n - D_;
            Kw[((size_t)(bb * H_ + (nk >> 6)) * S_ + ss) * HD_ + (nk & 63)] = f2b(v);
          }
        }
      }
    }
  } else {
#pragma unroll
    for (int i = 0; i < 4; ++i) {
#pragma unroll
      for (int r = 0; r < 4; ++r) {
        const int nv = n0 + wr * 64 + i * 16 + g * 4 + r;
        const float bias = bv[nv];
#pragma unroll
        for (int j = 0; j < 4; ++j) {
          const int m = m0 + wc * 64 + j * 16 + li;
          const int bb = m >> 10, ss = m & 1023;
          const float v = acc[i][j][r] + bias;
          Vt[((size_t)(bb * H_ + (nv >> 6)) * HD_ + (nv & 63)) * S_ + ss] = f2b(v);
        }
      }
    }
  }
}

// ---------------- kernel 3: flash attention, swapped-QK, DMA-staged prev ----------------
// prev (the 512MB HBM stream) goes global_load_lds -> per-wave-private LDS slots,
// double-buffered, one barrier drain per iter (m97 pattern). K/V/mask are register
// loads from L2/L3. sa = mfma(K,Q) -> D[k][q]: q=lane&15, k=4*(lane>>4)+reg.
__global__ __launch_bounds__(256, 3) void k_attn(const unsigned short* __restrict__ Qw,
    const unsigned short* __restrict__ Kw, const unsigned short* __restrict__ Vt,
    const float* __restrict__ prev, const float* __restrict__ mask,
    float* __restrict__ out) {
  __shared__ float pm_s[2][4][4][64][4];        // [buf][wave][cb][lane][4 f32] = 32 KB
  __shared__ unsigned short p_lds[4][16][72];   // P bounce (q-row major), 144B rows
  const int tid = threadIdx.x;
  const int lane = tid & 63, wv = tid >> 6;
  const int g = lane >> 4, li = lane & 15;

  const int phys = blockIdx.x + 16 * blockIdx.y;  // 0..2047
  const int xcd = phys & 7, idx = phys >> 3;
  const int qt = idx & 15;                        // consecutive same-XCD blocks: same bh
  const int bh = xcd + 8 * (idx >> 4);
  const int b = bh >> 4, h = bh & 15;
  const int q0 = qt * 64 + wv * 16;

  // per-lane DMA source / mask source: row (q0+li), col base g*4
  const float* pdma = prev + (size_t)bh * S_ * S_ + (size_t)(q0 + li) * S_ + g * 4;
  const float* mb   = mask + (size_t)b * S_ * S_ + (size_t)(q0 + li) * S_ + g * 4;
  const unsigned short* kbase = Kw + (size_t)bh * S_ * HD_;
  const unsigned short* vbase = Vt + (size_t)bh * HD_ * S_;

  // Q fragment (B-operand; row=li, k=g*8+e), pre-scaled by SCALE*LOG2E
  bf16x8 qf[2];
  {
    const unsigned short* qp = Qw + ((size_t)bh * S_ + q0 + li) * HD_ + g * 8;
    qf[0] = *(const bf16x8*)qp;
    qf[1] = *(const bf16x8*)(qp + 32);
  }

  // prologue: DMA pm tile 0 into buf 0
#pragma unroll
  for (int cb = 0; cb < 4; ++cb)
    __builtin_amdgcn_global_load_lds(
        (const __attribute__((address_space(1))) void*)(pdma + cb * 16),
        (__attribute__((address_space(3))) void*)&pm_s[0][wv][cb][0][0], 16, 0, 0);

  float lrun = 0.f;
  f32x4 ctx[4];
#pragma unroll
  for (int d = 0; d < 4; ++d) ctx[d] = (f32x4){0.f, 0.f, 0.f, 0.f};

  __syncthreads();   // drains prologue DMA

  int cur = 0;
  for (int t = 0; t < 16; ++t) {
    const int s0 = t * 64;

    // K(t) — L2-resident
    bf16x8 kf[4][2];
#pragma unroll
    for (int cb = 0; cb < 4; ++cb) {
      const unsigned short* kp = kbase + (size_t)(s0 + cb * 16 + li) * HD_ + g * 8;
      kf[cb][0] = *(const bf16x8*)kp;
      kf[cb][1] = *(const bf16x8*)(kp + 32);
    }
    // V(t) — L2-resident
    bf16x8 vf[4][2];
#pragma unroll
    for (int d = 0; d < 4; ++d) {
      const unsigned short* vp = vbase + (size_t)(d * 16 + li) * S_ + s0 + g * 8;
      vf[d][0] = *(const bf16x8*)vp;
      vf[d][1] = *(const bf16x8*)(vp + 32);
    }
    // mask(t) — L3-resident
    f32x4 mA[4];
#pragma unroll
    for (int cb = 0; cb < 4; ++cb) mA[cb] = *(const f32x4*)(mb + s0 + cb * 16);

    // QK swapped: D[k][q]
    f32x4 sa[4];
#pragma unroll
    for (int cb = 0; cb < 4; ++cb) {
      f32x4 z = (f32x4){0.f, 0.f, 0.f, 0.f};
      z      = __builtin_amdgcn_mfma_f32_16x16x32_bf16(kf[cb][0], qf[0], z, 0, 0, 0);
      sa[cb] = __builtin_amdgcn_mfma_f32_16x16x32_bf16(kf[cb][1], qf[1], z, 0, 0, 0);
    }

    // DMA prev(t+1) into the other buffer — issued after QK, drained only at barrier
    if (t < 15) {
#pragma unroll
      for (int cb = 0; cb < 4; ++cb)
        __builtin_amdgcn_global_load_lds(
            (const __attribute__((address_space(1))) void*)(pdma + s0 + 64 + cb * 16),
            (__attribute__((address_space(3))) void*)&pm_s[cur ^ 1][wv][cb][0][0], 16, 0, 0);
    }

    // p = exp2(sa + (prev+mask)*log2e - 20); per-lane row-sum
#pragma unroll
    for (int cb = 0; cb < 4; ++cb) {
      const f32x4 pv = *(const f32x4*)&pm_s[cur][wv][cb][lane][0];
      f32x4 pmc;
      pmc.x = fmaf(pv.x + mA[cb].x, LOG2E, -MSHIFT_);
      pmc.y = fmaf(pv.y + mA[cb].y, LOG2E, -MSHIFT_);
      pmc.z = fmaf(pv.z + mA[cb].z, LOG2E, -MSHIFT_);
      pmc.w = fmaf(pv.w + mA[cb].w, LOG2E, -MSHIFT_);
      const float e0 = exp2f(sa[cb][0] + pmc.x);
      const float e1 = exp2f(sa[cb][1] + pmc.y);
      const float e2 = exp2f(sa[cb][2] + pmc.z);
      const float e3 = exp2f(sa[cb][3] + pmc.w);
      lrun += (e0 + e1) + (e2 + e3);
      ushort4 pw;
      pw.x = f2b(e0); pw.y = f2b(e1); pw.z = f2b(e2); pw.w = f2b(e3);
      *(ushort4*)&p_lds[wv][li][cb * 16 + g * 4] = pw;
    }

    // P (A-layout) from per-wave bounce
    bf16x8 pf0 = *(const bf16x8*)&p_lds[wv][li][g * 8];
    bf16x8 pf1 = *(const bf16x8*)&p_lds[wv][li][32 + g * 8];
#pragma unroll
    for (int d = 0; d < 4; ++d) {
      ctx[d] = __builtin_amdgcn_mfma_f32_16x16x32_bf16(pf0, vf[d][0], ctx[d], 0, 0, 0);
      ctx[d] = __builtin_amdgcn_mfma_f32_16x16x32_bf16(pf1, vf[d][1], ctx[d], 0, 0, 0);
    }

    __syncthreads();   // single drain point: prev(t+1) DMA completes here
    cur ^= 1;
  }

  // row sums: combine the 4 g-groups (lane li holds partial for q-row li)
  lrun += __shfl_xor(lrun, 16);
  lrun += __shfl_xor(lrun, 32);
#pragma unroll
  for (int j = 0; j < 4; ++j) {
    const float rs = __shfl(lrun, g * 4 + j);
    const float inv = 1.0f / rs;
    const int q = q0 + g * 4 + j;
    float* op = out + ((size_t)b * S_ + q) * D_ + h * HD_ + li;
#pragma unroll
    for (int d = 0; d < 4; ++d)
      op[d * 16] = ctx[d][j] * inv;
  }
}

extern "C" void kernel_launch(void* const* d_in, const int* in_sizes, int n_in,
                              void* d_out, int out_size, void* d_ws, size_t ws_size,
                              hipStream_t stream) {
  const float* hs   = (const float*)d_in[0];
  const float* mask = (const float*)d_in[1];
  const float* prev = (const float*)d_in[2];
  const float* Wq   = (const float*)d_in[3];
  const float* bq   = (const float*)d_in[4];
  const float* Wk   = (const float*)d_in[5];
  const float* bk   = (const float*)d_in[6];
  const float* Wv   = (const float*)d_in[7];
  const float* bv   = (const float*)d_in[8];
  float* out = (float*)d_out;

  char* ws = (char*)d_ws;
  unsigned short* Xbf = (unsigned short*)ws;                    // 16 MB
  unsigned short* Wt  = (unsigned short*)(ws + (16ull << 20));  //  6 MB
  unsigned short* Qw  = (unsigned short*)(ws + (22ull << 20));  // 16 MB
  unsigned short* Kw  = (unsigned short*)(ws + (38ull << 20));  // 16 MB
  unsigned short* Vt  = (unsigned short*)(ws + (54ull << 20));  // 16 MB  (total 70 MB)

  k_convert_x<<<2048, 256, 0, stream>>>(hs, Xbf);
  k_transpose_w<<<dim3(16, 16, 3), 256, 0, stream>>>(Wq, Wk, Wv, Wt);
  k_proj<0><<<dim3(64, 16), 256, 0, stream>>>(Xbf, Wt, bq, bk, bv, Qw, Kw, Vt);
  k_proj<1><<<dim3(64, 8),  256, 0, stream>>>(Xbf, Wt, bq, bk, bv, Qw, Kw, Vt);
  k_attn<<<dim3(16, 128), 256, 0, stream>>>(Qw, Kw, Vt, prev, mask, out);
}

// Round 6
// 317.858 us; speedup vs baseline: 1.5775x; 1.3799x over previous
//
#include <hip/hip_runtime.h>

#define B_  8
#define S_  1024
#define D_  1024
#define H_  16
#define HD_ 64
#define M_  8192           // B*S
#define LOG2E 1.44269504088896f
#define QSCALE_ (0.125f * 1.44269504088896f)   // fold scale*log2e into Q
#define MSHIFT_ 20.0f      // static softmax shift (log2 domain)

typedef __attribute__((ext_vector_type(8))) short bf16x8;
typedef __attribute__((ext_vector_type(4))) float f32x4;

__device__ __forceinline__ unsigned short f2b(float x) {
  union { float f; unsigned u; } un; un.f = x;
  unsigned r = un.u + 0x7FFFu + ((un.u >> 16) & 1u);  // RNE
  return (unsigned short)(r >> 16);
}

// ---------------- kernel 0: hidden_states f32 -> bf16 ----------------
__global__ __launch_bounds__(256) void k_convert_x(const float* __restrict__ x,
                                                   unsigned short* __restrict__ o) {
  int i = (blockIdx.x * 256 + threadIdx.x) * 4;
  const int n = M_ * D_;
  const int stride = gridDim.x * 256 * 4;
  for (; i < n; i += stride) {
    const float4 v = *(const float4*)(x + i);
    ushort4 r;
    r.x = f2b(v.x); r.y = f2b(v.y); r.z = f2b(v.z); r.w = f2b(v.w);
    *(ushort4*)(o + i) = r;
  }
}

// ---------------- kernel 1: W (K x N) -> Wt bf16 (N x K), 3 matrices ----------------
__global__ __launch_bounds__(256) void k_transpose_w(const float* __restrict__ Wq,
    const float* __restrict__ Wk, const float* __restrict__ Wv,
    unsigned short* __restrict__ Wt) {
  __shared__ float t[64][65];
  const float* W = (blockIdx.z == 0) ? Wq : ((blockIdx.z == 1) ? Wk : Wv);
  unsigned short* dst = Wt + (size_t)blockIdx.z * (D_ * D_);
  const int k0 = blockIdx.x * 64, n0 = blockIdx.y * 64;
  const int tid = threadIdx.x;
#pragma unroll
  for (int i = 0; i < 16; ++i) {
    const int lin = i * 256 + tid;
    const int r = lin >> 6, c = lin & 63;
    t[r][c] = W[(size_t)(k0 + r) * D_ + n0 + c];
  }
  __syncthreads();
#pragma unroll
  for (int i = 0; i < 16; ++i) {
    const int lin = i * 256 + tid;
    const int r = lin >> 6, c = lin & 63;
    dst[(size_t)(n0 + r) * D_ + k0 + c] = f2b(t[c][r]);
  }
}

// ---------------- kernel 2: projection GEMM (m97 structure, 128x128x32) ----------------
template <int MODE>
__global__ __launch_bounds__(256) void k_proj(const unsigned short* __restrict__ X,
    const unsigned short* __restrict__ Wt,
    const float* __restrict__ bq, const float* __restrict__ bk, const float* __restrict__ bv,
    unsigned short* __restrict__ Qw, unsigned short* __restrict__ Kw,
    unsigned short* __restrict__ Vt) {
  __shared__ unsigned short xs[128 * 32];
  __shared__ unsigned short wsh[128 * 32];
  const int tid = threadIdx.x;
  const int lane = tid & 63, wv = tid >> 6;
  const int g = lane >> 4, li = lane & 15;
  const int m0 = blockIdx.x * 128;
  const int n0 = blockIdx.y * 128;
  const int wr = wv >> 1, wc = wv & 1;
  const int wtrow0 = (MODE == 0) ? n0 : (2048 + n0);

  f32x4 acc[4][4];
#pragma unroll
  for (int i = 0; i < 4; ++i)
#pragma unroll
    for (int j = 0; j < 4; ++j) acc[i][j] = (f32x4){0.f, 0.f, 0.f, 0.f};

  const int srow = wv * 32 + (lane >> 2);
  const int skel = (lane & 3) * 8;

  for (int k0 = 0; k0 < D_; k0 += 32) {
#pragma unroll
    for (int i = 0; i < 2; ++i) {
      const unsigned short* gx = X + (size_t)(m0 + srow + i * 16) * D_ + k0 + skel;
      const unsigned short* gw = Wt + (size_t)(wtrow0 + srow + i * 16) * D_ + k0 + skel;
      __builtin_amdgcn_global_load_lds(
          (const __attribute__((address_space(1))) void*)gx,
          (__attribute__((address_space(3))) void*)&xs[(wv * 32 + i * 16) * 32], 16, 0, 0);
      __builtin_amdgcn_global_load_lds(
          (const __attribute__((address_space(1))) void*)gw,
          (__attribute__((address_space(3))) void*)&wsh[(wv * 32 + i * 16) * 32], 16, 0, 0);
    }
    __syncthreads();
    bf16x8 af[4], bfr[4];
#pragma unroll
    for (int i = 0; i < 4; ++i) {
      const int ar = wr * 64 + i * 16 + li;
      const int br = wc * 64 + i * 16 + li;
      if (MODE == 0) {
        af[i]  = *(const bf16x8*)&xs[ar * 32 + g * 8];
        bfr[i] = *(const bf16x8*)&wsh[br * 32 + g * 8];
      } else {
        af[i]  = *(const bf16x8*)&wsh[ar * 32 + g * 8];
        bfr[i] = *(const bf16x8*)&xs[br * 32 + g * 8];
      }
    }
#pragma unroll
    for (int i = 0; i < 4; ++i)
#pragma unroll
      for (int j = 0; j < 4; ++j)
        acc[i][j] = __builtin_amdgcn_mfma_f32_16x16x32_bf16(af[i], bfr[j], acc[i][j], 0, 0, 0);
    __syncthreads();
  }

  if (MODE == 0) {
#pragma unroll
    for (int j = 0; j < 4; ++j) {
      const int n = n0 + wc * 64 + j * 16 + li;
      const float bias = (n < D_) ? bq[n] : bk[n - D_];
#pragma unroll
      for (int i = 0; i < 4; ++i) {
#pragma unroll
        for (int r = 0; r < 4; ++r) {
          const int m = m0 + wr * 64 + i * 16 + g * 4 + r;
          const float v = acc[i][j][r] + bias;
          const int bb = m >> 10, ss = m & 1023;
          if (n < D_) {
            Qw[((size_t)(bb * H_ + (n >> 6)) * S_ + ss) * HD_ + (n & 63)] = f2b(v * QSCALE_);
          } else {
            const int nk = n - D_;
            Kw[((size_t)(bb * H_ + (nk >> 6)) * S_ + ss) * HD_ + (nk & 63)] = f2b(v);
          }
        }
      }
    }
  } else {
#pragma unroll
    for (int i = 0; i < 4; ++i) {
#pragma unroll
      for (int r = 0; r < 4; ++r) {
        const int nv = n0 + wr * 64 + i * 16 + g * 4 + r;
        const float bias = bv[nv];
#pragma unroll
        for (int j = 0; j < 4; ++j) {
          const int m = m0 + wc * 64 + j * 16 + li;
          const int bb = m >> 10, ss = m & 1023;
          const float v = acc[i][j][r] + bias;
          Vt[((size_t)(bb * H_ + (nv >> 6)) * HD_ + (nv & 63)) * S_ + ss] = f2b(v);
        }
      }
    }
  }
}

// ---------------- kernel 3: flash attention, all streams DMA-staged in LDS ----------------
// K/V tiles: block-shared LDS dbuf, XOR-swizzled (source-side) against 128B-row bank
// conflicts. prev: per-wave LDS dbuf. mask: register loads (L3), issued BEFORE the DMAs
// so its vmcnt wait keeps them in flight. All t+1 DMAs issue at top of iter t; one
// barrier per iter is the only drain point. No global load feeds an MFMA via VGPRs.
__global__ __launch_bounds__(256, 2) void k_attn(const unsigned short* __restrict__ Qw,
    const unsigned short* __restrict__ Kw, const unsigned short* __restrict__ Vt,
    const float* __restrict__ prev, const float* __restrict__ mask,
    float* __restrict__ out) {
  __shared__ unsigned short k_s[2][4096];       // 64 rows x 64 cols bf16, 8 KB/buf
  __shared__ unsigned short v_s[2][4096];       // 64 dcols x 64 s, 8 KB/buf
  __shared__ float pm_s[2][4][4][64][4];        // [buf][wave][cb][lane][4 f32] = 16 KB/buf
  __shared__ unsigned short p_lds[4][16][72];   // P bounce (q-row major), 144B rows
  const int tid = threadIdx.x;
  const int lane = tid & 63, wv = tid >> 6;
  const int g = lane >> 4, li = lane & 15;

  const int phys = blockIdx.x + 16 * blockIdx.y;  // 0..2047
  const int xcd = phys & 7, idx = phys >> 3;
  const int qt = idx & 15;                        // consecutive same-XCD blocks: same bh
  const int bh = xcd + 8 * (idx >> 4);
  const int b = bh >> 4, h = bh & 15;
  const int q0 = qt * 64 + wv * 16;

  const float* pdma = prev + (size_t)bh * S_ * S_ + (size_t)(q0 + li) * S_ + g * 4;
  const float* mb   = mask + (size_t)b * S_ * S_ + (size_t)(q0 + li) * S_ + g * 4;
  const unsigned short* kbase = Kw + (size_t)bh * S_ * HD_;
  const unsigned short* vbase = Vt + (size_t)bh * HD_ * S_;

  // Q fragment (B-operand; row=li, k=g*8+e), pre-scaled by SCALE*LOG2E
  bf16x8 qf[2];
  {
    const unsigned short* qp = Qw + ((size_t)bh * S_ + q0 + li) * HD_ + g * 8;
    qf[0] = *(const bf16x8*)qp;
    qf[1] = *(const bf16x8*)(qp + 32);
  }

  // K/V DMA thread mapping: chunk o16 = i*256+tid -> row=o16>>3, c16=o16&7.
  // Source chunk is XOR-swizzled (c16 ^ row&7); LDS dest is linear (rule #21).
  const int dr0 = (0 * 256 + tid) >> 3, dc0 = (0 * 256 + tid) & 7;
  const int dr1 = (1 * 256 + tid) >> 3, dc1 = (1 * 256 + tid) & 7;
  const int sc0 = ((dc0 ^ (dr0 & 7)) << 3);
  const int sc1 = ((dc1 ^ (dr1 & 7)) << 3);

#define STAGE(TN, BI)                                                                      \
  {                                                                                        \
    const int sn = (TN) * 64;                                                              \
    __builtin_amdgcn_global_load_lds(                                                      \
        (const __attribute__((address_space(1))) void*)(kbase + (size_t)(sn + dr0) * HD_ + sc0), \
        (__attribute__((address_space(3))) void*)(&k_s[BI][0] + wv * 512), 16, 0, 0);      \
    __builtin_amdgcn_global_load_lds(                                                      \
        (const __attribute__((address_space(1))) void*)(kbase + (size_t)(sn + dr1) * HD_ + sc1), \
        (__attribute__((address_space(3))) void*)(&k_s[BI][0] + 2048 + wv * 512), 16, 0, 0); \
    __builtin_amdgcn_global_load_lds(                                                      \
        (const __attribute__((address_space(1))) void*)(vbase + (size_t)dr0 * S_ + sn + sc0), \
        (__attribute__((address_space(3))) void*)(&v_s[BI][0] + wv * 512), 16, 0, 0);      \
    __builtin_amdgcn_global_load_lds(                                                      \
        (const __attribute__((address_space(1))) void*)(vbase + (size_t)dr1 * S_ + sn + sc1), \
        (__attribute__((address_space(3))) void*)(&v_s[BI][0] + 2048 + wv * 512), 16, 0, 0); \
    _Pragma("unroll")                                                                      \
    for (int cb = 0; cb < 4; ++cb)                                                         \
      __builtin_amdgcn_global_load_lds(                                                    \
          (const __attribute__((address_space(1))) void*)(pdma + sn + cb * 16),            \
          (__attribute__((address_space(3))) void*)&pm_s[BI][wv][cb][0][0], 16, 0, 0);     \
  }

  float lrun = 0.f;
  f32x4 ctx[4];
#pragma unroll
  for (int d = 0; d < 4; ++d) ctx[d] = (f32x4){0.f, 0.f, 0.f, 0.f};

  // prologue: stage tile 0 into buf 0
  STAGE(0, 0);
  __syncthreads();

  int cur = 0;
  for (int t = 0; t < 16; ++t) {
    // mask(t) register loads FIRST (so waiting on them leaves the DMAs in flight)
    f32x4 mA[4];
#pragma unroll
    for (int cb = 0; cb < 4; ++cb) mA[cb] = *(const f32x4*)(mb + t * 64 + cb * 16);

    // DMA tile t+1 into the other buffers — a full iteration of latency tolerance
    if (t < 15) STAGE(t + 1, cur ^ 1);

    // QK from swizzled K LDS: sa = mfma(K,Q) -> D[k][q], q=li, k=4g+reg
    const unsigned short* kb = &k_s[cur][0];
    const unsigned short* vb = &v_s[cur][0];
    f32x4 sa[4];
#pragma unroll
    for (int cb = 0; cb < 4; ++cb) {
      const int r = cb * 16 + li;
      const bf16x8 k0 = *(const bf16x8*)(kb + r * 64 + ((g ^ (li & 7)) << 3));
      const bf16x8 k1 = *(const bf16x8*)(kb + r * 64 + (((g + 4) ^ (li & 7)) << 3));
      f32x4 z = (f32x4){0.f, 0.f, 0.f, 0.f};
      z      = __builtin_amdgcn_mfma_f32_16x16x32_bf16(k0, qf[0], z, 0, 0, 0);
      sa[cb] = __builtin_amdgcn_mfma_f32_16x16x32_bf16(k1, qf[1], z, 0, 0, 0);
    }

    // p = exp2(sa + (prev+mask)*log2e - 20); per-lane row-sum (q=li)
#pragma unroll
    for (int cb = 0; cb < 4; ++cb) {
      const f32x4 pv = *(const f32x4*)&pm_s[cur][wv][cb][lane][0];
      f32x4 pmc;
      pmc.x = fmaf(pv.x + mA[cb].x, LOG2E, -MSHIFT_);
      pmc.y = fmaf(pv.y + mA[cb].y, LOG2E, -MSHIFT_);
      pmc.z = fmaf(pv.z + mA[cb].z, LOG2E, -MSHIFT_);
      pmc.w = fmaf(pv.w + mA[cb].w, LOG2E, -MSHIFT_);
      const float e0 = exp2f(sa[cb][0] + pmc.x);
      const float e1 = exp2f(sa[cb][1] + pmc.y);
      const float e2 = exp2f(sa[cb][2] + pmc.z);
      const float e3 = exp2f(sa[cb][3] + pmc.w);
      lrun += (e0 + e1) + (e2 + e3);
      ushort4 pw;
      pw.x = f2b(e0); pw.y = f2b(e1); pw.z = f2b(e2); pw.w = f2b(e3);
      *(ushort4*)&p_lds[wv][li][cb * 16 + g * 4] = pw;
    }

    // P (A-layout) from per-wave bounce; V from swizzled LDS
    bf16x8 pf0 = *(const bf16x8*)&p_lds[wv][li][g * 8];
    bf16x8 pf1 = *(const bf16x8*)&p_lds[wv][li][32 + g * 8];
#pragma unroll
    for (int d = 0; d < 4; ++d) {
      const int r = d * 16 + li;
      const bf16x8 v0 = *(const bf16x8*)(vb + r * 64 + ((g ^ (li & 7)) << 3));
      const bf16x8 v1 = *(const bf16x8*)(vb + r * 64 + (((g + 4) ^ (li & 7)) << 3));
      ctx[d] = __builtin_amdgcn_mfma_f32_16x16x32_bf16(pf0, v0, ctx[d], 0, 0, 0);
      ctx[d] = __builtin_amdgcn_mfma_f32_16x16x32_bf16(pf1, v1, ctx[d], 0, 0, 0);
    }

    __syncthreads();   // single drain point: tile t+1 DMAs complete here
    cur ^= 1;
  }
#undef STAGE

  // row sums: combine the 4 g-groups (lane li holds partial for q-row li)
  lrun += __shfl_xor(lrun, 16);
  lrun += __shfl_xor(lrun, 32);
#pragma unroll
  for (int j = 0; j < 4; ++j) {
    const float rs = __shfl(lrun, g * 4 + j);
    const float inv = 1.0f / rs;
    const int q = q0 + g * 4 + j;
    float* op = out + ((size_t)b * S_ + q) * D_ + h * HD_ + li;
#pragma unroll
    for (int d = 0; d < 4; ++d)
      op[d * 16] = ctx[d][j] * inv;
  }
}

extern "C" void kernel_launch(void* const* d_in, const int* in_sizes, int n_in,
                              void* d_out, int out_size, void* d_ws, size_t ws_size,
                              hipStream_t stream) {
  const float* hs   = (const float*)d_in[0];
  const float* mask = (const float*)d_in[1];
  const float* prev = (const float*)d_in[2];
  const float* Wq   = (const float*)d_in[3];
  const float* bq   = (const float*)d_in[4];
  const float* Wk   = (const float*)d_in[5];
  const float* bk   = (const float*)d_in[6];
  const float* Wv   = (const float*)d_in[7];
  const float* bv   = (const float*)d_in[8];
  float* out = (float*)d_out;

  char* ws = (char*)d_ws;
  unsigned short* Xbf = (unsigned short*)ws;                    // 16 MB
  unsigned short* Wt  = (unsigned short*)(ws + (16ull << 20));  //  6 MB
  unsigned short* Qw  = (unsigned short*)(ws + (22ull << 20));  // 16 MB
  unsigned short* Kw  = (unsigned short*)(ws + (38ull << 20));  // 16 MB
  unsigned short* Vt  = (unsigned short*)(ws + (54ull << 20));  // 16 MB  (total 70 MB)

  k_convert_x<<<2048, 256, 0, stream>>>(hs, Xbf);
  k_transpose_w<<<dim3(16, 16, 3), 256, 0, stream>>>(Wq, Wk, Wv, Wt);
  k_proj<0><<<dim3(64, 16), 256, 0, stream>>>(Xbf, Wt, bq, bk, bv, Qw, Kw, Vt);
  k_proj<1><<<dim3(64, 8),  256, 0, stream>>>(Xbf, Wt, bq, bk, bv, Qw, Kw, Vt);
  k_attn<<<dim3(16, 128), 256, 0, stream>>>(Qw, Kw, Vt, prev, mask, out);
}

// Round 7
// 284.970 us; speedup vs baseline: 1.7595x; 1.1154x over previous
//
#include <hip/hip_runtime.h>

#define B_  8
#define S_  1024
#define D_  1024
#define H_  16
#define HD_ 64
#define M_  8192           // B*S
#define LOG2E 1.44269504088896f
#define QSCALE_ (0.125f * 1.44269504088896f)   // fold scale*log2e into Q
#define MSHIFT_ 20.0f      // static softmax shift (log2 domain)

typedef __attribute__((ext_vector_type(8))) short bf16x8;
typedef __attribute__((ext_vector_type(4))) float f32x4;

__device__ __forceinline__ unsigned short f2b(float x) {
  union { float f; unsigned u; } un; un.f = x;
  unsigned r = un.u + 0x7FFFu + ((un.u >> 16) & 1u);  // RNE
  return (unsigned short)(r >> 16);
}

// ---------------- kernel 0: hidden_states f32 -> bf16 ----------------
__global__ __launch_bounds__(256) void k_convert_x(const float* __restrict__ x,
                                                   unsigned short* __restrict__ o) {
  int i = (blockIdx.x * 256 + threadIdx.x) * 4;
  const int n = M_ * D_;
  const int stride = gridDim.x * 256 * 4;
  for (; i < n; i += stride) {
    const float4 v = *(const float4*)(x + i);
    ushort4 r;
    r.x = f2b(v.x); r.y = f2b(v.y); r.z = f2b(v.z); r.w = f2b(v.w);
    *(ushort4*)(o + i) = r;
  }
}

// ---------------- kernel 1: W (K x N) -> Wt bf16 (N x K), 3 matrices ----------------
__global__ __launch_bounds__(256) void k_transpose_w(const float* __restrict__ Wq,
    const float* __restrict__ Wk, const float* __restrict__ Wv,
    unsigned short* __restrict__ Wt) {
  __shared__ float t[64][65];
  const float* W = (blockIdx.z == 0) ? Wq : ((blockIdx.z == 1) ? Wk : Wv);
  unsigned short* dst = Wt + (size_t)blockIdx.z * (D_ * D_);
  const int k0 = blockIdx.x * 64, n0 = blockIdx.y * 64;
  const int tid = threadIdx.x;
#pragma unroll
  for (int i = 0; i < 16; ++i) {
    const int lin = i * 256 + tid;
    const int r = lin >> 6, c = lin & 63;
    t[r][c] = W[(size_t)(k0 + r) * D_ + n0 + c];
  }
  __syncthreads();
#pragma unroll
  for (int i = 0; i < 16; ++i) {
    const int lin = i * 256 + tid;
    const int r = lin >> 6, c = lin & 63;
    dst[(size_t)(n0 + r) * D_ + k0 + c] = f2b(t[c][r]);
  }
}

// ---------------- kernel 2: projection GEMM (m97 structure, 128x128x32) ----------------
template <int MODE>
__global__ __launch_bounds__(256) void k_proj(const unsigned short* __restrict__ X,
    const unsigned short* __restrict__ Wt,
    const float* __restrict__ bq, const float* __restrict__ bk, const float* __restrict__ bv,
    unsigned short* __restrict__ Qw, unsigned short* __restrict__ Kw,
    unsigned short* __restrict__ Vt) {
  __shared__ unsigned short xs[128 * 32];
  __shared__ unsigned short wsh[128 * 32];
  const int tid = threadIdx.x;
  const int lane = tid & 63, wv = tid >> 6;
  const int g = lane >> 4, li = lane & 15;
  const int m0 = blockIdx.x * 128;
  const int n0 = blockIdx.y * 128;
  const int wr = wv >> 1, wc = wv & 1;
  const int wtrow0 = (MODE == 0) ? n0 : (2048 + n0);

  f32x4 acc[4][4];
#pragma unroll
  for (int i = 0; i < 4; ++i)
#pragma unroll
    for (int j = 0; j < 4; ++j) acc[i][j] = (f32x4){0.f, 0.f, 0.f, 0.f};

  const int srow = wv * 32 + (lane >> 2);
  const int skel = (lane & 3) * 8;

  for (int k0 = 0; k0 < D_; k0 += 32) {
#pragma unroll
    for (int i = 0; i < 2; ++i) {
      const unsigned short* gx = X + (size_t)(m0 + srow + i * 16) * D_ + k0 + skel;
      const unsigned short* gw = Wt + (size_t)(wtrow0 + srow + i * 16) * D_ + k0 + skel;
      __builtin_amdgcn_global_load_lds(
          (const __attribute__((address_space(1))) void*)gx,
          (__attribute__((address_space(3))) void*)&xs[(wv * 32 + i * 16) * 32], 16, 0, 0);
      __builtin_amdgcn_global_load_lds(
          (const __attribute__((address_space(1))) void*)gw,
          (__attribute__((address_space(3))) void*)&wsh[(wv * 32 + i * 16) * 32], 16, 0, 0);
    }
    __syncthreads();
    bf16x8 af[4], bfr[4];
#pragma unroll
    for (int i = 0; i < 4; ++i) {
      const int ar = wr * 64 + i * 16 + li;
      const int br = wc * 64 + i * 16 + li;
      if (MODE == 0) {
        af[i]  = *(const bf16x8*)&xs[ar * 32 + g * 8];
        bfr[i] = *(const bf16x8*)&wsh[br * 32 + g * 8];
      } else {
        af[i]  = *(const bf16x8*)&wsh[ar * 32 + g * 8];
        bfr[i] = *(const bf16x8*)&xs[br * 32 + g * 8];
      }
    }
#pragma unroll
    for (int i = 0; i < 4; ++i)
#pragma unroll
      for (int j = 0; j < 4; ++j)
        acc[i][j] = __builtin_amdgcn_mfma_f32_16x16x32_bf16(af[i], bfr[j], acc[i][j], 0, 0, 0);
    __syncthreads();
  }

  if (MODE == 0) {
#pragma unroll
    for (int j = 0; j < 4; ++j) {
      const int n = n0 + wc * 64 + j * 16 + li;
      const float bias = (n < D_) ? bq[n] : bk[n - D_];
#pragma unroll
      for (int i = 0; i < 4; ++i) {
#pragma unroll
        for (int r = 0; r < 4; ++r) {
          const int m = m0 + wr * 64 + i * 16 + g * 4 + r;
          const float v = acc[i][j][r] + bias;
          const int bb = m >> 10, ss = m & 1023;
          if (n < D_) {
            Qw[((size_t)(bb * H_ + (n >> 6)) * S_ + ss) * HD_ + (n & 63)] = f2b(v * QSCALE_);
          } else {
            const int nk = n - D_;
            Kw[((size_t)(bb * H_ + (nk >> 6)) * S_ + ss) * HD_ + (nk & 63)] = f2b(v);
          }
        }
      }
    }
  } else {
#pragma unroll
    for (int i = 0; i < 4; ++i) {
#pragma unroll
      for (int r = 0; r < 4; ++r) {
        const int nv = n0 + wr * 64 + i * 16 + g * 4 + r;
        const float bias = bv[nv];
#pragma unroll
        for (int j = 0; j < 4; ++j) {
          const int m = m0 + wc * 64 + j * 16 + li;
          const int bb = m >> 10, ss = m & 1023;
          const float v = acc[i][j][r] + bias;
          Vt[((size_t)(bb * H_ + (nv >> 6)) * HD_ + (nv & 63)) * S_ + ss] = f2b(v);
        }
      }
    }
  }
}

// ---------------- kernel 3: flash attention, counted-vmcnt LDS pipeline ----------------
// All operand streams DMA-staged (global_load_lds). Raw s_barrier + hand-counted
// s_waitcnt vmcnt(12) (never 0 in the loop): each phase issues exactly 12 VMEM ops
// (8 DMA + 4 mask register loads), waits only the PREVIOUS phase's 12, leaving the
// current prefetch in flight across both barriers. Static dbuf indices via x2 unroll.
__global__ __launch_bounds__(256, 2) void k_attn(const unsigned short* __restrict__ Qw,
    const unsigned short* __restrict__ Kw, const unsigned short* __restrict__ Vt,
    const float* __restrict__ prev, const float* __restrict__ mask,
    float* __restrict__ out) {
  __shared__ unsigned short k_s[2][4096];       // 64 rows x 64 cols bf16, 8 KB/buf
  __shared__ unsigned short v_s[2][4096];       // 64 dcols x 64 s, 8 KB/buf
  __shared__ float pm_s[2][4][4][64][4];        // [buf][wave][cb][lane][4 f32] = 16 KB/buf
  __shared__ unsigned short p_lds[4][16][72];   // P bounce (q-row major), 144B rows
  const int tid = threadIdx.x;
  const int lane = tid & 63, wv = tid >> 6;
  const int g = lane >> 4, li = lane & 15;

  const int phys = blockIdx.x + 16 * blockIdx.y;  // 0..2047
  const int xcd = phys & 7, idx = phys >> 3;
  const int qt = idx & 15;                        // consecutive same-XCD blocks: same bh
  const int bh = xcd + 8 * (idx >> 4);
  const int b = bh >> 4, h = bh & 15;
  const int q0 = qt * 64 + wv * 16;

  const float* pdma = prev + (size_t)bh * S_ * S_ + (size_t)(q0 + li) * S_ + g * 4;
  const float* mb   = mask + (size_t)b * S_ * S_ + (size_t)(q0 + li) * S_ + g * 4;
  const unsigned short* kbase = Kw + (size_t)bh * S_ * HD_;
  const unsigned short* vbase = Vt + (size_t)bh * HD_ * S_;

  // Q fragment (B-operand; row=li, k=g*8+e), pre-scaled by SCALE*LOG2E
  bf16x8 qf[2];
  {
    const unsigned short* qp = Qw + ((size_t)bh * S_ + q0 + li) * HD_ + g * 8;
    qf[0] = *(const bf16x8*)qp;
    qf[1] = *(const bf16x8*)(qp + 32);
  }

  // K/V DMA thread mapping: chunk o16 = i*256+tid -> row=o16>>3, c16=o16&7.
  // Source chunk is XOR-swizzled (c16 ^ row&7); LDS dest is linear (rule #21).
  const int dr0 = (0 * 256 + tid) >> 3, dc0 = (0 * 256 + tid) & 7;
  const int dr1 = (1 * 256 + tid) >> 3, dc1 = (1 * 256 + tid) & 7;
  const int sc0 = ((dc0 ^ (dr0 & 7)) << 3);
  const int sc1 = ((dc1 ^ (dr1 & 7)) << 3);

  // 8 global_load_lds per phase per wave
#define STAGE(TN, BI)                                                                      \
  {                                                                                        \
    const int sn = (TN) * 64;                                                              \
    __builtin_amdgcn_global_load_lds(                                                      \
        (const __attribute__((address_space(1))) void*)(kbase + (size_t)(sn + dr0) * HD_ + sc0), \
        (__attribute__((address_space(3))) void*)(&k_s[BI][0] + wv * 512), 16, 0, 0);      \
    __builtin_amdgcn_global_load_lds(                                                      \
        (const __attribute__((address_space(1))) void*)(kbase + (size_t)(sn + dr1) * HD_ + sc1), \
        (__attribute__((address_space(3))) void*)(&k_s[BI][0] + 2048 + wv * 512), 16, 0, 0); \
    __builtin_amdgcn_global_load_lds(                                                      \
        (const __attribute__((address_space(1))) void*)(vbase + (size_t)dr0 * S_ + sn + sc0), \
        (__attribute__((address_space(3))) void*)(&v_s[BI][0] + wv * 512), 16, 0, 0);      \
    __builtin_amdgcn_global_load_lds(                                                      \
        (const __attribute__((address_space(1))) void*)(vbase + (size_t)dr1 * S_ + sn + sc1), \
        (__attribute__((address_space(3))) void*)(&v_s[BI][0] + 2048 + wv * 512), 16, 0, 0); \
    _Pragma("unroll")                                                                      \
    for (int cb = 0; cb < 4; ++cb)                                                         \
      __builtin_amdgcn_global_load_lds(                                                    \
          (const __attribute__((address_space(1))) void*)(pdma + sn + cb * 16),            \
          (__attribute__((address_space(3))) void*)&pm_s[BI][wv][cb][0][0], 16, 0, 0);     \
  }

  float lrun = 0.f;
  f32x4 ctx[4];
#pragma unroll
  for (int d = 0; d < 4; ++d) ctx[d] = (f32x4){0.f, 0.f, 0.f, 0.f};

  f32x4 mA[4], mB[4];

  // prologue: stage tile 0 into buf 0 + mask(0) -> mA  (12 VMEM ops, not waited here)
  STAGE(0, 0);
#pragma unroll
  for (int cb = 0; cb < 4; ++cb) mA[cb] = *(const f32x4*)(mb + cb * 16);

  // Phase: STAGE(t+1,NB) + mask(t+1) [12 ops] -> vmcnt(12) [prev phase's 12 done,
  // current 12 stay in flight] -> barrier -> compute(buf PB, MCUR) -> barrier (WAR).
#define PHASE(T, PB, NB, MCUR, MNXT)                                                  \
  {                                                                                   \
    const int tn = ((T) < 15) ? (T) + 1 : 15;                                         \
    STAGE(tn, NB);                                                                    \
    _Pragma("unroll")                                                                 \
    for (int cb = 0; cb < 4; ++cb)                                                    \
      MNXT[cb] = *(const f32x4*)(mb + tn * 64 + cb * 16);                             \
    asm volatile("s_waitcnt vmcnt(12)" ::: "memory");                                 \
    __builtin_amdgcn_s_barrier();                                                     \
    {                                                                                 \
      const unsigned short* kb = &k_s[PB][0];                                         \
      const unsigned short* vb = &v_s[PB][0];                                         \
      f32x4 sa[4];                                                                    \
      _Pragma("unroll")                                                               \
      for (int cb = 0; cb < 4; ++cb) {                                                \
        const int r = cb * 16 + li;                                                   \
        const bf16x8 k0 = *(const bf16x8*)(kb + r * 64 + ((g ^ (li & 7)) << 3));      \
        const bf16x8 k1 = *(const bf16x8*)(kb + r * 64 + (((g + 4) ^ (li & 7)) << 3)); \
        f32x4 z = (f32x4){0.f, 0.f, 0.f, 0.f};                                        \
        z      = __builtin_amdgcn_mfma_f32_16x16x32_bf16(k0, qf[0], z, 0, 0, 0);      \
        sa[cb] = __builtin_amdgcn_mfma_f32_16x16x32_bf16(k1, qf[1], z, 0, 0, 0);      \
      }                                                                               \
      _Pragma("unroll")                                                               \
      for (int cb = 0; cb < 4; ++cb) {                                                \
        const f32x4 pv = *(const f32x4*)&pm_s[PB][wv][cb][lane][0];                   \
        f32x4 pmc;                                                                    \
        pmc.x = fmaf(pv.x + MCUR[cb].x, LOG2E, -MSHIFT_);                             \
        pmc.y = fmaf(pv.y + MCUR[cb].y, LOG2E, -MSHIFT_);                             \
        pmc.z = fmaf(pv.z + MCUR[cb].z, LOG2E, -MSHIFT_);                             \
        pmc.w = fmaf(pv.w + MCUR[cb].w, LOG2E, -MSHIFT_);                             \
        const float e0 = exp2f(sa[cb][0] + pmc.x);                                    \
        const float e1 = exp2f(sa[cb][1] + pmc.y);                                    \
        const float e2 = exp2f(sa[cb][2] + pmc.z);                                    \
        const float e3 = exp2f(sa[cb][3] + pmc.w);                                    \
        lrun += (e0 + e1) + (e2 + e3);                                                \
        ushort4 pw;                                                                   \
        pw.x = f2b(e0); pw.y = f2b(e1); pw.z = f2b(e2); pw.w = f2b(e3);               \
        *(ushort4*)&p_lds[wv][li][cb * 16 + g * 4] = pw;                              \
      }                                                                               \
      bf16x8 pf0 = *(const bf16x8*)&p_lds[wv][li][g * 8];                             \
      bf16x8 pf1 = *(const bf16x8*)&p_lds[wv][li][32 + g * 8];                        \
      _Pragma("unroll")                                                               \
      for (int d = 0; d < 4; ++d) {                                                   \
        const int r = d * 16 + li;                                                    \
        const bf16x8 v0 = *(const bf16x8*)(vb + r * 64 + ((g ^ (li & 7)) << 3));      \
        const bf16x8 v1 = *(const bf16x8*)(vb + r * 64 + (((g + 4) ^ (li & 7)) << 3)); \
        ctx[d] = __builtin_amdgcn_mfma_f32_16x16x32_bf16(pf0, v0, ctx[d], 0, 0, 0);   \
        ctx[d] = __builtin_amdgcn_mfma_f32_16x16x32_bf16(pf1, v1, ctx[d], 0, 0, 0);   \
      }                                                                               \
    }                                                                                 \
    __builtin_amdgcn_s_barrier();                                                     \
  }

  for (int t = 0; t < 16; t += 2) {
    PHASE(t,     0, 1, mA, mB);
    PHASE(t + 1, 1, 0, mB, mA);
  }
#undef PHASE
#undef STAGE

  // row sums: combine the 4 g-groups (lane li holds partial for q-row li)
  lrun += __shfl_xor(lrun, 16);
  lrun += __shfl_xor(lrun, 32);
#pragma unroll
  for (int j = 0; j < 4; ++j) {
    const float rs = __shfl(lrun, g * 4 + j);
    const float inv = 1.0f / rs;
    const int q = q0 + g * 4 + j;
    float* op = out + ((size_t)b * S_ + q) * D_ + h * HD_ + li;
#pragma unroll
    for (int d = 0; d < 4; ++d)
      op[d * 16] = ctx[d][j] * inv;
  }
}

extern "C" void kernel_launch(void* const* d_in, const int* in_sizes, int n_in,
                              void* d_out, int out_size, void* d_ws, size_t ws_size,
                              hipStream_t stream) {
  const float* hs   = (const float*)d_in[0];
  const float* mask = (const float*)d_in[1];
  const float* prev = (const float*)d_in[2];
  const float* Wq   = (const float*)d_in[3];
  const float* bq   = (const float*)d_in[4];
  const float* Wk   = (const float*)d_in[5];
  const float* bk   = (const float*)d_in[6];
  const float* Wv   = (const float*)d_in[7];
  const float* bv   = (const float*)d_in[8];
  float* out = (float*)d_out;

  char* ws = (char*)d_ws;
  unsigned short* Xbf = (unsigned short*)ws;                    // 16 MB
  unsigned short* Wt  = (unsigned short*)(ws + (16ull << 20));  //  6 MB
  unsigned short* Qw  = (unsigned short*)(ws + (22ull << 20));  // 16 MB
  unsigned short* Kw  = (unsigned short*)(ws + (38ull << 20));  // 16 MB
  unsigned short* Vt  = (unsigned short*)(ws + (54ull << 20));  // 16 MB  (total 70 MB)

  k_convert_x<<<2048, 256, 0, stream>>>(hs, Xbf);
  k_transpose_w<<<dim3(16, 16, 3), 256, 0, stream>>>(Wq, Wk, Wv, Wt);
  k_proj<0><<<dim3(64, 16), 256, 0, stream>>>(Xbf, Wt, bq, bk, bv, Qw, Kw, Vt);
  k_proj<1><<<dim3(64, 8),  256, 0, stream>>>(Xbf, Wt, bq, bk, bv, Qw, Kw, Vt);
  k_attn<<<dim3(16, 128), 256, 0, stream>>>(Qw, Kw, Vt, prev, mask, out);
}